// Round 13
// baseline (297.131 us; speedup 1.0000x reference)
//
#include <hip/hip_runtime.h>

typedef __bf16 bf16;
typedef __bf16 bf16x8 __attribute__((ext_vector_type(8)));
typedef float f32x4 __attribute__((ext_vector_type(4)));

#define DEPTH   18
#define N_NODES ((1 << DEPTH) - 1)      // 262143
#define KDIM    192                     // E + 2H
#define RDIM    320                     // 3H + 2H
#define A_PAD   200                     // padded A-row stride (bf16 elems)
#define LOG2E   1.4426950408889634f

__device__ __forceinline__ float rcpf(float x) { return __builtin_amdgcn_rcpf(x); }
// pre-activations pre-scaled by log2e (folded into Wcat/bias)
__device__ __forceinline__ float sig2(float p)  { return rcpf(1.f + exp2f(-p)); }
__device__ __forceinline__ float tanhf_(float x){ return 2.f * rcpf(1.f + exp2f(-2.f * LOG2E * x)) - 1.f; }

// shared epilogue: acc[5] + biases + children c -> c4, h4
__device__ __forceinline__ void gates(const f32x4* acc,
        const float4& bI, const float4& bO, const float4& bU,
        const float4& bL, const float4& bR,
        const float4& cl, const float4& cr, float4& c4, float4& h4) {
    const float* pbI = &bI.x; const float* pbO = &bO.x; const float* pbU = &bU.x;
    const float* pbL = &bL.x; const float* pbR = &bR.x;
    const float* pcl = &cl.x; const float* pcr = &cr.x;
    float* pc4 = &c4.x; float* ph4 = &h4.x;
#pragma unroll
    for (int r = 0; r < 4; r++) {
        float i_g = sig2(acc[0][r] + pbI[r]);
        float o_g = sig2(acc[1][r] + pbO[r]);
        float u_g = tanhf_(sig2(acc[2][r] + pbU[r]));   // ref: tanh(sigmoid(pre_u))
        float fl  = sig2(acc[3][r] + pbL[r]);
        float fr  = sig2(acc[4][r] + pbR[r]);
        float c = i_g * u_g + fl * pcl[r] + fr * pcr[r];
        pc4[r] = c;
        ph4[r] = o_g * tanhf_(c);
    }
}

// ---- dispatch 1: blocks 0..511 elementwise pack (Wcat, bias, emb16);
// blocks 512..543 leaf tables (independent: convert own W/emb slices). ----
__global__ void prep_all(const float* __restrict__ emb,
                     const float* __restrict__ W_iou, const float* __restrict__ U_iou,
                     const float* __restrict__ W_f,   const float* __restrict__ U_f,
                     const float* __restrict__ b_Wiou, const float* __restrict__ b_Uiou,
                     const float* __restrict__ b_Wf,   const float* __restrict__ b_Uf,
                     bf16* __restrict__ Wcat, float* __restrict__ bias, bf16* __restrict__ emb16,
                     bf16* __restrict__ leafH, float* __restrict__ leafC) {
    __shared__ __align__(16) bf16 Wl[192 * 72];
    __shared__ __align__(16) bf16 Al[64 * 72];
    const int blk = blockIdx.x, tid = threadIdx.x;
    if (blk < 512) {
        int t = blk * 256 + tid;                 // t < 131072 == 2048*64
        emb16[t] = (bf16)emb[t];
        if (t < RDIM * KDIM) {
            int r = t / KDIM, k = t % KDIM;
            float v;
            if (r < 192) v = (k < 64) ? W_iou[r * 64 + k] : U_iou[r * 128 + (k - 64)];
            else { int rr = r - 192; v = (k < 64) ? W_f[rr * 64 + k] : U_f[rr * 128 + (k - 64)]; }
            Wcat[t] = (bf16)(v * LOG2E);
        }
        if (t < RDIM)
            bias[t] = ((t < 192) ? (b_Wiou[t] + b_Uiou[t]) : (b_Wf[t - 192] + b_Uf[t - 192])) * LOG2E;
        return;
    }
    // ---- leaf-table block: vocab slice [v0, v0+64) ----
    const int v0 = (blk - 512) * 64;
    for (int i = tid; i < 192 * 64; i += 256) {
        int r = i >> 6, k = i & 63;
        Wl[r * 72 + k] = (bf16)(W_iou[i] * LOG2E);
    }
    for (int i = tid; i < 64 * 64; i += 256) {
        int r = i >> 6, k = i & 63;
        Al[r * 72 + k] = (bf16)emb[(v0 << 6) + i];
    }
    __syncthreads();
    const int wave = tid >> 6, lane = tid & 63;
    const int l15 = lane & 15, quad = lane >> 4;
    const int jw = (wave & 3) * 16, jb = jw + quad * 4;

    f32x4 acc[4][3];
#pragma unroll
    for (int t = 0; t < 4; t++)
#pragma unroll
        for (int g = 0; g < 3; g++) acc[t][g] = (f32x4){0.f, 0.f, 0.f, 0.f};
#pragma unroll
    for (int kb = 0; kb < 2; kb++) {
        bf16x8 wfrag[3], nfrag[4];
#pragma unroll
        for (int g = 0; g < 3; g++)
            wfrag[g] = *(const bf16x8*)(&Wl[(g * 64 + jw + l15) * 72 + kb * 32 + quad * 8]);
#pragma unroll
        for (int t = 0; t < 4; t++)
            nfrag[t] = *(const bf16x8*)(&Al[(t * 16 + l15) * 72 + kb * 32 + quad * 8]);
#pragma unroll
        for (int t = 0; t < 4; t++)
#pragma unroll
            for (int g = 0; g < 3; g++)
                acc[t][g] = __builtin_amdgcn_mfma_f32_16x16x32_bf16(wfrag[g], nfrag[t], acc[t][g], 0, 0, 0);
    }
    float4 bW, bU_;
    bW = *(const float4*)(b_Wiou + jb);       bU_ = *(const float4*)(b_Uiou + jb);
    float4 bI = make_float4((bW.x + bU_.x) * LOG2E, (bW.y + bU_.y) * LOG2E, (bW.z + bU_.z) * LOG2E, (bW.w + bU_.w) * LOG2E);
    bW = *(const float4*)(b_Wiou + 64 + jb);  bU_ = *(const float4*)(b_Uiou + 64 + jb);
    float4 bO = make_float4((bW.x + bU_.x) * LOG2E, (bW.y + bU_.y) * LOG2E, (bW.z + bU_.z) * LOG2E, (bW.w + bU_.w) * LOG2E);
    bW = *(const float4*)(b_Wiou + 128 + jb); bU_ = *(const float4*)(b_Uiou + 128 + jb);
    float4 bU = make_float4((bW.x + bU_.x) * LOG2E, (bW.y + bU_.y) * LOG2E, (bW.z + bU_.z) * LOG2E, (bW.w + bU_.w) * LOG2E);
    const float* pbI = &bI.x; const float* pbO = &bO.x; const float* pbU = &bU.x;
#pragma unroll
    for (int t = 0; t < 4; t++) {
        int v = v0 + t * 16 + l15;
        float4 c4; float* pc4 = &c4.x;
        union { bf16 h[4]; uint2 u; } hp;
#pragma unroll
        for (int r = 0; r < 4; r++) {
            float i_g = sig2(acc[t][0][r] + pbI[r]);
            float o_g = sig2(acc[t][1][r] + pbO[r]);
            float u_g = tanhf_(sig2(acc[t][2][r] + pbU[r]));
            float c = i_g * u_g;
            pc4[r] = c;
            hp.h[r] = (bf16)(o_g * tanhf_(c));
        }
        *(float4*)(leafC + (size_t)v * 64 + jb) = c4;
        *(uint2*)(leafH + (size_t)v * 64 + jb) = hp.u;
    }
}

// ---- generic level phase for big_pass (levels 15..8). Computes level l
// (m nodes) from Acur; h + x staged into Anx; c passed through the FREE HIGH
// ROWS of Anx (byte offset (m/2)*A_PAD*2 — verified to fit every level) so
// inter-level c never touches HBM. CGLOB: level-15 reads level-16 c from
// global c_buf (prefetched to regs). Level 8 (l==8) writes c,h to global.
// wt is 4-way (16 waves); ti stride 4. ----
template<int NQ, bool CGLOB>
__device__ __forceinline__ void level_phase(
        int l, int blk, int tid, int wt, int l15, int quad, int jb,
        const bf16x8 (&Wf)[5][6],
        const float4& bI, const float4& bO, const float4& bU,
        const float4& bL, const float4& bR,
        bf16* Acur, bf16* Anx,
        const bf16* __restrict__ emb16, const int* __restrict__ token_ids,
        bf16* __restrict__ H, float* __restrict__ c_buf)
{
    const int m = 1 << (l - 8);
    const int s = (1 << l) - 1, o = blk * m;
    const int T = (m + 15) >> 4;
    const int mn = m >> 1;
    const float* Cin = (const float*)(Acur + m * A_PAD);   // children c (level l+1), LDS

    // ---- prefetch c for my tiles (static unroll -> stays in VGPRs) ----
    float4 pcl[NQ], pcr[NQ];
    int pidx[NQ], pgn[NQ]; bool pact[NQ];
#pragma unroll
    for (int q = 0; q < NQ; q++) {
        int ti = wt + 4 * q;
        int idx0 = ti * 16 + l15;
        bool act = (ti < T) && (idx0 < m);
        int idx = act ? idx0 : 0;
        pidx[q] = idx; pact[q] = act; pgn[q] = s + o + idx;
        if (CGLOB) {
            pcl[q] = *(const float4*)(c_buf + (size_t)(2 * pgn[q] + 1) * 64 + jb);
            pcr[q] = *(const float4*)(c_buf + (size_t)(2 * pgn[q] + 2) * 64 + jb);
        } else {
            pcl[q] = *(const float4*)(Cin + (2 * idx) * 68 + jb);
            pcr[q] = *(const float4*)(Cin + (2 * idx + 1) * 68 + jb);
        }
    }

    // ---- staging split part A: next-level token ids -> regs ----
    int tok = 0;
    const int srow = tid >> 3, sk8 = (tid & 7) << 3;
    const bool sact = (l > 8) && (tid < mn * 8);
    if (sact) tok = token_ids[(1 << (l - 1)) - 1 + blk * mn + srow];

    // ---- compute tiles ----
    float* Cout = (float*)(Anx + mn * A_PAD);
#pragma unroll
    for (int q = 0; q < NQ; q++) {
        f32x4 acc[5];
#pragma unroll
        for (int g = 0; g < 5; g++) acc[g] = (f32x4){0.f, 0.f, 0.f, 0.f};
#pragma unroll
        for (int kb = 0; kb < 6; kb++) {
            bf16x8 nf = *(const bf16x8*)(&Acur[pidx[q] * A_PAD + kb * 32 + quad * 8]);
#pragma unroll
            for (int g = 0; g < 5; g++)
                acc[g] = __builtin_amdgcn_mfma_f32_16x16x32_bf16(Wf[g][kb], nf, acc[g], 0, 0, 0);
        }
        float4 c4, h4;
        gates(acc, bI, bO, bU, bL, bR, pcl[q], pcr[q], c4, h4);
        if (pact[q]) {
            union { bf16 h[4]; uint2 u; } hp;
            const float* ph4 = &h4.x;
#pragma unroll
            for (int r = 0; r < 4; r++) hp.h[r] = (bf16)ph4[r];
            if (l > 8) {
                *(float4*)(Cout + pidx[q] * 68 + jb) = c4;
                *(uint2*)(&Anx[(pidx[q] >> 1) * A_PAD + 64 + (pidx[q] & 1) * 64 + jb]) = hp.u;
            } else {
                *(float4*)(c_buf + (size_t)pgn[q] * 64 + jb) = c4;
                *(uint2*)(H + (size_t)pgn[q] * 64 + jb) = hp.u;
            }
        }
    }

    // ---- staging split part B: gather + LDS write (token arrived under compute) ----
    if (sact) {
        uint4 g = *(const uint4*)(emb16 + (size_t)tok * 64 + sk8);
        *(uint4*)(&Anx[srow * A_PAD + sk8]) = g;
    }
    __syncthreads();
}

// ---- dispatch 2: levels 16..8, 256 blocks x 1024 thr (16 waves: wj 4-way
// j-slice, wt 4-way tile split). One chain per CU (LDS 153.6 KB) but 4
// waves/SIMD (vs R6's 2) to hide the ~50% stall fraction R12's counters
// showed (busy = 7.5us MFMA + 21us VALU of 58us total).
// __launch_bounds__(1024, 1): measured cap model is 256/min_waves_arg —
// (512,2)=124, (512,4)=64, (1024,default)=64 all fit; (1024,1) -> cap 256,
// natural allocation 128 VGPR = exactly the 16-wave/CU HW limit.
// REVERT SIGNAL: VGPR 64 or FETCH >100 MB (scratch spill, R3/R5/R11). ----
__global__ __launch_bounds__(1024, 1) void big_pass(
        const bf16* __restrict__ Wcat, const float* __restrict__ bias,
        const bf16* __restrict__ emb16, const int* __restrict__ token_ids,
        const bf16* __restrict__ leafH, const float* __restrict__ leafC,
        bf16* __restrict__ H, float* __restrict__ c_buf) {
    __shared__ __align__(16) bf16 A0[256 * A_PAD];   // 102400 B
    __shared__ __align__(16) bf16 A1[128 * A_PAD];   //  51200 B (total 153600 B)
    const int tid = threadIdx.x, blk = blockIdx.x;
    const int wave = tid >> 6, lane = tid & 63;
    const int l15 = lane & 15, quad = lane >> 4;
    const int wj = wave & 3, wt = wave >> 2;         // wj 0..3, wt 0..3
    const int jw = wj * 16, jb = jw + quad * 4;

    const int base16 = 65535 + blk * 256;            // first level-16 node of this block

    // ---- stage level-16 tile: x (token emb gather) + children h (leaf table) ----
    for (int ch = tid; ch < 256 * 8; ch += 1024) {
        int row = ch >> 3, k8 = (ch & 7) << 3;
        int tok = token_ids[base16 + row];
        *(uint4*)&A0[row * A_PAD + k8] = *(const uint4*)(emb16 + tok * 64 + k8);
    }
    for (int ch = tid; ch < 256 * 16; ch += 1024) {
        int row = ch >> 4, half = (ch >> 3) & 1, k8 = (ch & 7) << 3;
        int tok = token_ids[2 * (base16 + row) + 1 + half];
        *(uint4*)&A0[row * A_PAD + 64 + half * 64 + k8] = *(const uint4*)(leafH + (size_t)tok * 64 + k8);
    }

    // prefetch level-16 epilogue grandchild tokens (leafC 1-hop later)
    int tkl16[4], tkr16[4];
#pragma unroll
    for (int q = 0; q < 4; q++) {
        int idx = (wt + 4 * q) * 16 + l15;           // ti = wt,wt+4,wt+8,wt+12 < 16
        int gn = base16 + idx;
        tkl16[q] = token_ids[2 * gn + 1];
        tkr16[q] = token_ids[2 * gn + 2];
    }
    // prefetch level-15 staging token (128 rows x 8 chunks == exactly 1/thread)
    const int rowa = tid >> 3, k8a = (tid & 7) << 3;
    const int tok15a = token_ids[32767 + blk * 128 + rowa];

    // loop-invariant W fragments -> registers (30 x bf16x8), reused for 9 levels
    bf16x8 Wf[5][6];
#pragma unroll
    for (int g = 0; g < 5; g++)
#pragma unroll
        for (int kb = 0; kb < 6; kb++)
            Wf[g][kb] = *(const bf16x8*)(Wcat + (g * 64 + jw + l15) * KDIM + kb * 32 + quad * 8);

    const float4 bI = *(const float4*)(bias + jb);
    const float4 bO = *(const float4*)(bias + 64 + jb);
    const float4 bU = *(const float4*)(bias + 128 + jb);
    const float4 bL = *(const float4*)(bias + 192 + jb);
    const float4 bR = *(const float4*)(bias + 256 + jb);
    __syncthreads();

    // ---- level 16: 16 tiles, 4/wave-group, two groups of 2 with
    //      reg-prefetched leafC c ----
#pragma unroll
    for (int grp = 0; grp < 2; grp++) {
        float4 cl4[2], cr4[2];
#pragma unroll
        for (int q = 0; q < 2; q++) {
            cl4[q] = *(const float4*)(leafC + (size_t)tkl16[grp * 2 + q] * 64 + jb);
            cr4[q] = *(const float4*)(leafC + (size_t)tkr16[grp * 2 + q] * 64 + jb);
        }
#pragma unroll
        for (int q = 0; q < 2; q++) {
            const int idx = (wt + 4 * (grp * 2 + q)) * 16 + l15;     // < 256 always
            const int gn = base16 + idx;
            f32x4 acc[5];
#pragma unroll
            for (int g = 0; g < 5; g++) acc[g] = (f32x4){0.f, 0.f, 0.f, 0.f};
#pragma unroll
            for (int kb = 0; kb < 6; kb++) {
                bf16x8 nf = *(const bf16x8*)(&A0[idx * A_PAD + kb * 32 + quad * 8]);
#pragma unroll
                for (int g = 0; g < 5; g++)
                    acc[g] = __builtin_amdgcn_mfma_f32_16x16x32_bf16(Wf[g][kb], nf, acc[g], 0, 0, 0);
            }
            float4 c4, h4;
            gates(acc, bI, bO, bU, bL, bR, cl4[q], cr4[q], c4, h4);
            union { bf16 h[4]; uint2 u; } hp;
            const float* ph4 = &h4.x;
#pragma unroll
            for (int r = 0; r < 4; r++) hp.h[r] = (bf16)ph4[r];
            *(float4*)(c_buf + (size_t)gn * 64 + jb) = c4;           // level-16 c: global (L2)
            *(uint2*)(&A1[(idx >> 1) * A_PAD + 64 + (idx & 1) * 64 + jb]) = hp.u;
        }
        if (grp == 0) {
            // issue level-15 x gather (token arrived under group-0 compute)
            uint4 ga = *(const uint4*)(emb16 + (size_t)tok15a * 64 + k8a);
            *(uint4*)(&A1[rowa * A_PAD + k8a]) = ga;
        }
    }
    __syncthreads();

    // ---- levels 15..8 via level_phase; c through LDS from 15 down ----
    bf16* Acur = A1;
    bf16* Anx  = A0;
    level_phase<2, true >(15, blk, tid, wt, l15, quad, jb, Wf, bI, bO, bU, bL, bR,
                          Acur, Anx, emb16, token_ids, H, c_buf);
    { bf16* t = Acur; Acur = Anx; Anx = t; }
    for (int l = 14; l >= 8; l--) {
        level_phase<1, false>(l, blk, tid, wt, l15, quad, jb, Wf, bI, bO, bU, bL, bR,
                              Acur, Anx, emb16, token_ids, H, c_buf);
        bf16* t = Acur; Acur = Anx; Anx = t;
    }
}

// ---- dispatch 3: levels 7..0, ONE block x 512 thr (8 waves), fully
// LDS-resident. All global gathers hoisted into one overlapped staging phase
// before the first barrier; inter-level h in one packed A-tile, inter-level c
// ping-pongs between two LDS f32 buffers. ----
__global__ __launch_bounds__(512) void tail_pass(
        const bf16* __restrict__ Wcat, const float* __restrict__ bias,
        const bf16* __restrict__ emb16, const int* __restrict__ token_ids,
        const bf16* __restrict__ H, const float* __restrict__ c_buf,
        float* __restrict__ out) {
    __shared__ __align__(16) bf16 A[255 * A_PAD];   // 102000 B: x+h for levels 7..0
    __shared__ __align__(16) float C0[128 * 68];    //  34816 B
    __shared__ __align__(16) float C1[64 * 68];     //  17408 B  (total 154224 B)
    const int tid = threadIdx.x;
    const int wave = tid >> 6, lane = tid & 63;
    const int l15 = lane & 15, quad = lane >> 4;
    const int wj = wave & 3, wt = wave >> 2;
    const int jw = wj * 16, jb = jw + quad * 4;

    // prefetch level-7 children c (level-8 c_buf) into regs; fully unrolled so
    // cl7/cr7 stay in VGPRs. Latency overlaps the LDS staging below.
    float4 cl7[4], cr7[4];
#pragma unroll
    for (int q = 0; q < 4; q++) {
        int idx = (wt + 2 * q) * 16 + l15;
        int gn = 127 + idx;
        cl7[q] = *(const float4*)(c_buf + (size_t)(2 * gn + 1) * 64 + jb);
        cr7[q] = *(const float4*)(c_buf + (size_t)(2 * gn + 2) * 64 + jb);
    }

    // stage x (emb16 gather) for ALL levels 7..0: row r -> level l = 31-clz(255-r),
    // idx = r - (256 - 2^(l+1)); 2040 independent 16B loads across 512 threads.
    for (int ch = tid; ch < 255 * 8; ch += 512) {
        int row = ch >> 3, k8 = (ch & 7) << 3;
        int l = 31 - __clz(255 - row);
        int idx = row - 256 + (2 << l);
        int gn = (1 << l) - 1 + idx;
        int tok = token_ids[gn];
        *(uint4*)&A[row * A_PAD + k8] = *(const uint4*)(emb16 + tok * 64 + k8);
    }
    // stage level-7 children h (level-8 H rows, contiguous sibling pairs)
    for (int ch = tid; ch < 128 * 16; ch += 512) {
        int row = ch >> 4, k8 = (ch & 15) << 3;
        *(uint4*)&A[row * A_PAD + 64 + k8] =
            *(const uint4*)(H + (size_t)(255 + 2 * row) * 64 + k8);
    }

    // loop-invariant W fragments
    bf16x8 Wf[5][6];
#pragma unroll
    for (int g = 0; g < 5; g++)
#pragma unroll
        for (int kb = 0; kb < 6; kb++)
            Wf[g][kb] = *(const bf16x8*)(Wcat + (g * 64 + jw + l15) * KDIM + kb * 32 + quad * 8);

    const float4 bI = *(const float4*)(bias + jb);
    const float4 bO = *(const float4*)(bias + 64 + jb);
    const float4 bU = *(const float4*)(bias + 128 + jb);
    const float4 bL = *(const float4*)(bias + 192 + jb);
    const float4 bR = *(const float4*)(bias + 256 + jb);
    __syncthreads();

    // ---- level 7 (128 nodes, 8 tiles; c from prefetched regs) ----
#pragma unroll
    for (int q = 0; q < 4; q++) {
        const int idx = (wt + 2 * q) * 16 + l15;     // < 128 always
        f32x4 acc[5];
#pragma unroll
        for (int g = 0; g < 5; g++) acc[g] = (f32x4){0.f, 0.f, 0.f, 0.f};
#pragma unroll
        for (int kb = 0; kb < 6; kb++) {
            bf16x8 nf = *(const bf16x8*)(&A[idx * A_PAD + kb * 32 + quad * 8]);
#pragma unroll
            for (int g = 0; g < 5; g++)
                acc[g] = __builtin_amdgcn_mfma_f32_16x16x32_bf16(Wf[g][kb], nf, acc[g], 0, 0, 0);
        }
        float4 c4, h4;
        gates(acc, bI, bO, bU, bL, bR, cl7[q], cr7[q], c4, h4);
        union { bf16 h[4]; uint2 u; } hp;
        const float* ph4 = &h4.x;
#pragma unroll
        for (int r = 0; r < 4; r++) hp.h[r] = (bf16)ph4[r];
        *(float4*)(C0 + idx * 68 + jb) = c4;                               // level-7 c
        *(uint2*)(&A[(128 + (idx >> 1)) * A_PAD + 64 + (idx & 1) * 64 + jb]) = hp.u;
    }
    __syncthreads();

    // ---- levels 6..0, all data in LDS ----
    float* Ccur = C0;
    float* Cnx  = C1;
    for (int l = 6; l >= 0; l--) {
        const int n = 1 << l;
        const int off  = 256 - 2 * n;    // this level's A-row offset
        const int offn = 256 - n;        // next (parent) level's A-row offset
        const int T = (n + 15) >> 4;
        for (int ti = wt; ti < T; ti += 2) {
            int idx0 = ti * 16 + l15;
            int idx = idx0 < n ? idx0 : n - 1;
            float4 cl = *(const float4*)(Ccur + (2 * idx) * 68 + jb);
            float4 cr = *(const float4*)(Ccur + (2 * idx + 1) * 68 + jb);
            f32x4 acc[5];
#pragma unroll
            for (int g = 0; g < 5; g++) acc[g] = (f32x4){0.f, 0.f, 0.f, 0.f};
#pragma unroll
            for (int kb = 0; kb < 6; kb++) {
                bf16x8 nf = *(const bf16x8*)(&A[(off + idx) * A_PAD + kb * 32 + quad * 8]);
#pragma unroll
                for (int g = 0; g < 5; g++)
                    acc[g] = __builtin_amdgcn_mfma_f32_16x16x32_bf16(Wf[g][kb], nf, acc[g], 0, 0, 0);
            }
            float4 c4, h4;
            gates(acc, bI, bO, bU, bL, bR, cl, cr, c4, h4);
            if (idx0 < n) {
                if (l > 0) {
                    union { bf16 h[4]; uint2 u; } hp;
                    const float* ph4 = &h4.x;
#pragma unroll
                    for (int r = 0; r < 4; r++) hp.h[r] = (bf16)ph4[r];
                    *(float4*)(Cnx + idx * 68 + jb) = c4;
                    *(uint2*)(&A[(offn + (idx >> 1)) * A_PAD + 64 + (idx & 1) * 64 + jb]) = hp.u;
                } else {
                    *(float4*)(out + jb) = h4;        // stack([h, c]): h
                    *(float4*)(out + 64 + jb) = c4;   // c
                }
            }
        }
        __syncthreads();
        float* t = Ccur; Ccur = Cnx; Cnx = t;
    }
}

extern "C" void kernel_launch(void* const* d_in, const int* in_sizes, int n_in,
                              void* d_out, int out_size, void* d_ws, size_t ws_size,
                              hipStream_t stream) {
    const int*   token_ids = (const int*)d_in[0];
    const float* emb       = (const float*)d_in[1];
    const float* W_iou     = (const float*)d_in[2];
    const float* b_Wiou    = (const float*)d_in[3];
    const float* U_iou     = (const float*)d_in[4];
    const float* b_Uiou    = (const float*)d_in[5];
    const float* W_f       = (const float*)d_in[6];
    const float* b_Wf      = (const float*)d_in[7];
    const float* U_f       = (const float*)d_in[8];
    const float* b_Uf      = (const float*)d_in[9];
    float* out = (float*)d_out;

    // Compact workspace (~34.8 MB): H holds only level-8 h (512 rows);
    // c_buf holds nodes < 131072 (level-16 + level-8 writes only —
    // levels 15..9 c passes through LDS inside big_pass).
    char* ws = (char*)d_ws;
    bf16*  Wcat  = (bf16*)ws;                               // 122880 B
    float* bias  = (float*)(ws + 122880);                   // 1280 B -> 124160
    bf16*  emb16 = (bf16*)(ws + 124160);                    // 262144 B -> 386304
    bf16*  leafH = (bf16*)(ws + 386304);                    // 262144 B -> 648448
    float* leafC = (float*)(ws + 648448);                   // 524288 B -> 1172736
    bf16*  H     = (bf16*)(ws + 1172736);                   // 65536 B -> 1238272
    float* c_buf = (float*)(ws + 1238272);                  // 33554432 B -> 34792704

    prep_all<<<544, 256, 0, stream>>>(emb, W_iou, U_iou, W_f, U_f,
                                      b_Wiou, b_Uiou, b_Wf, b_Uf,
                                      Wcat, bias, emb16, leafH, leafC);
    big_pass<<<256, 1024, 0, stream>>>(Wcat, bias, emb16, token_ids, leafH, leafC, H, c_buf);
    tail_pass<<<1, 512, 0, stream>>>(Wcat, bias, emb16, token_ids, H, c_buf, out);
}

// Round 14
// 159.985 us; speedup vs baseline: 1.8572x; 1.8572x over previous
//
#include <hip/hip_runtime.h>

typedef __bf16 bf16;
typedef __bf16 bf16x8 __attribute__((ext_vector_type(8)));
typedef float f32x4 __attribute__((ext_vector_type(4)));

#define DEPTH   18
#define N_NODES ((1 << DEPTH) - 1)      // 262143
#define KDIM    192                     // E + 2H
#define RDIM    320                     // 3H + 2H
#define A_PAD   200                     // padded A-row stride (bf16 elems)
#define LOG2E   1.4426950408889634f

__device__ __forceinline__ float rcpf(float x) { return __builtin_amdgcn_rcpf(x); }
// pre-activations pre-scaled by log2e (folded into Wcat/bias)
__device__ __forceinline__ float sig2(float p)  { return rcpf(1.f + exp2f(-p)); }
__device__ __forceinline__ float tanhf_(float x){ return 2.f * rcpf(1.f + exp2f(-2.f * LOG2E * x)) - 1.f; }

// shared epilogue: acc[5] + biases + children c -> c4, h4
__device__ __forceinline__ void gates(const f32x4* acc,
        const float4& bI, const float4& bO, const float4& bU,
        const float4& bL, const float4& bR,
        const float4& cl, const float4& cr, float4& c4, float4& h4) {
    const float* pbI = &bI.x; const float* pbO = &bO.x; const float* pbU = &bU.x;
    const float* pbL = &bL.x; const float* pbR = &bR.x;
    const float* pcl = &cl.x; const float* pcr = &cr.x;
    float* pc4 = &c4.x; float* ph4 = &h4.x;
#pragma unroll
    for (int r = 0; r < 4; r++) {
        float i_g = sig2(acc[0][r] + pbI[r]);
        float o_g = sig2(acc[1][r] + pbO[r]);
        float u_g = tanhf_(sig2(acc[2][r] + pbU[r]));   // ref: tanh(sigmoid(pre_u))
        float fl  = sig2(acc[3][r] + pbL[r]);
        float fr  = sig2(acc[4][r] + pbR[r]);
        float c = i_g * u_g + fl * pcl[r] + fr * pcr[r];
        pc4[r] = c;
        ph4[r] = o_g * tanhf_(c);
    }
}

// ---- dispatch 1: blocks 0..511 elementwise pack (Wcat, bias, emb16);
// blocks 512..543 leaf tables (independent: convert own W/emb slices). ----
__global__ void prep_all(const float* __restrict__ emb,
                     const float* __restrict__ W_iou, const float* __restrict__ U_iou,
                     const float* __restrict__ W_f,   const float* __restrict__ U_f,
                     const float* __restrict__ b_Wiou, const float* __restrict__ b_Uiou,
                     const float* __restrict__ b_Wf,   const float* __restrict__ b_Uf,
                     bf16* __restrict__ Wcat, float* __restrict__ bias, bf16* __restrict__ emb16,
                     bf16* __restrict__ leafH, float* __restrict__ leafC) {
    __shared__ __align__(16) bf16 Wl[192 * 72];
    __shared__ __align__(16) bf16 Al[64 * 72];
    const int blk = blockIdx.x, tid = threadIdx.x;
    if (blk < 512) {
        int t = blk * 256 + tid;                 // t < 131072 == 2048*64
        emb16[t] = (bf16)emb[t];
        if (t < RDIM * KDIM) {
            int r = t / KDIM, k = t % KDIM;
            float v;
            if (r < 192) v = (k < 64) ? W_iou[r * 64 + k] : U_iou[r * 128 + (k - 64)];
            else { int rr = r - 192; v = (k < 64) ? W_f[rr * 64 + k] : U_f[rr * 128 + (k - 64)]; }
            Wcat[t] = (bf16)(v * LOG2E);
        }
        if (t < RDIM)
            bias[t] = ((t < 192) ? (b_Wiou[t] + b_Uiou[t]) : (b_Wf[t - 192] + b_Uf[t - 192])) * LOG2E;
        return;
    }
    // ---- leaf-table block: vocab slice [v0, v0+64) ----
    const int v0 = (blk - 512) * 64;
    for (int i = tid; i < 192 * 64; i += 256) {
        int r = i >> 6, k = i & 63;
        Wl[r * 72 + k] = (bf16)(W_iou[i] * LOG2E);
    }
    for (int i = tid; i < 64 * 64; i += 256) {
        int r = i >> 6, k = i & 63;
        Al[r * 72 + k] = (bf16)emb[(v0 << 6) + i];
    }
    __syncthreads();
    const int wave = tid >> 6, lane = tid & 63;
    const int l15 = lane & 15, quad = lane >> 4;
    const int jw = (wave & 3) * 16, jb = jw + quad * 4;

    f32x4 acc[4][3];
#pragma unroll
    for (int t = 0; t < 4; t++)
#pragma unroll
        for (int g = 0; g < 3; g++) acc[t][g] = (f32x4){0.f, 0.f, 0.f, 0.f};
#pragma unroll
    for (int kb = 0; kb < 2; kb++) {
        bf16x8 wfrag[3], nfrag[4];
#pragma unroll
        for (int g = 0; g < 3; g++)
            wfrag[g] = *(const bf16x8*)(&Wl[(g * 64 + jw + l15) * 72 + kb * 32 + quad * 8]);
#pragma unroll
        for (int t = 0; t < 4; t++)
            nfrag[t] = *(const bf16x8*)(&Al[(t * 16 + l15) * 72 + kb * 32 + quad * 8]);
#pragma unroll
        for (int t = 0; t < 4; t++)
#pragma unroll
            for (int g = 0; g < 3; g++)
                acc[t][g] = __builtin_amdgcn_mfma_f32_16x16x32_bf16(wfrag[g], nfrag[t], acc[t][g], 0, 0, 0);
    }
    float4 bW, bU_;
    bW = *(const float4*)(b_Wiou + jb);       bU_ = *(const float4*)(b_Uiou + jb);
    float4 bI = make_float4((bW.x + bU_.x) * LOG2E, (bW.y + bU_.y) * LOG2E, (bW.z + bU_.z) * LOG2E, (bW.w + bU_.w) * LOG2E);
    bW = *(const float4*)(b_Wiou + 64 + jb);  bU_ = *(const float4*)(b_Uiou + 64 + jb);
    float4 bO = make_float4((bW.x + bU_.x) * LOG2E, (bW.y + bU_.y) * LOG2E, (bW.z + bU_.z) * LOG2E, (bW.w + bU_.w) * LOG2E);
    bW = *(const float4*)(b_Wiou + 128 + jb); bU_ = *(const float4*)(b_Uiou + 128 + jb);
    float4 bU = make_float4((bW.x + bU_.x) * LOG2E, (bW.y + bU_.y) * LOG2E, (bW.z + bU_.z) * LOG2E, (bW.w + bU_.w) * LOG2E);
    const float* pbI = &bI.x; const float* pbO = &bO.x; const float* pbU = &bU.x;
#pragma unroll
    for (int t = 0; t < 4; t++) {
        int v = v0 + t * 16 + l15;
        float4 c4; float* pc4 = &c4.x;
        union { bf16 h[4]; uint2 u; } hp;
#pragma unroll
        for (int r = 0; r < 4; r++) {
            float i_g = sig2(acc[t][0][r] + pbI[r]);
            float o_g = sig2(acc[t][1][r] + pbO[r]);
            float u_g = tanhf_(sig2(acc[t][2][r] + pbU[r]));
            float c = i_g * u_g;
            pc4[r] = c;
            hp.h[r] = (bf16)(o_g * tanhf_(c));
        }
        *(float4*)(leafC + (size_t)v * 64 + jb) = c4;
        *(uint2*)(leafH + (size_t)v * 64 + jb) = hp.u;
    }
}

// ---- generic level phase for big_pass (levels 15..8). Computes level l
// (m nodes) from Acur; h + x staged into Anx; c passed through the FREE HIGH
// ROWS of Anx so inter-level c never touches HBM. CGLOB: level-15 reads
// level-16 c from c_buf (prefetched to regs). Level 8 writes c,h to global.
// NEW (R14): waves with wt >= T skip the dummy tile entirely (wave-uniform
// branch) — on levels 12..8 (T=1) this frees the co-SIMD wave's MFMA+trans
// issue bandwidth instead of burning it on discarded work. ----
template<int NQ, bool CGLOB>
__device__ __forceinline__ void level_phase(
        int l, int blk, int tid, int wt, int l15, int quad, int jb,
        const bf16x8 (&Wf)[5][6],
        const float4& bI, const float4& bO, const float4& bU,
        const float4& bL, const float4& bR,
        bf16* Acur, bf16* Anx,
        const bf16* __restrict__ emb16, const int* __restrict__ token_ids,
        bf16* __restrict__ H, float* __restrict__ c_buf)
{
    const int m = 1 << (l - 8);
    const int s = (1 << l) - 1, o = blk * m;
    const int T = (m + 15) >> 4;
    const int mn = m >> 1;
    const float* Cin = (const float*)(Acur + m * A_PAD);   // children c (level l+1), LDS

    // ---- staging split part A: next-level token ids -> regs ----
    int tok = 0;
    const int srow = tid >> 3, sk8 = (tid & 7) << 3;
    const bool sact = (l > 8) && (tid < mn * 8);
    if (sact) tok = token_ids[(1 << (l - 1)) - 1 + blk * mn + srow];

    if (wt < T) {   // wave-uniform: skip dummy tiles on T=1 levels
        // ---- prefetch c for my tiles (static unroll -> stays in VGPRs) ----
        float4 pcl[NQ], pcr[NQ];
        int pidx[NQ], pgn[NQ]; bool pact[NQ];
#pragma unroll
        for (int q = 0; q < NQ; q++) {
            int ti = wt + 2 * q;
            int idx0 = ti * 16 + l15;
            bool act = (ti < T) && (idx0 < m);
            int idx = act ? idx0 : 0;
            pidx[q] = idx; pact[q] = act; pgn[q] = s + o + idx;
            if (CGLOB) {
                pcl[q] = *(const float4*)(c_buf + (size_t)(2 * pgn[q] + 1) * 64 + jb);
                pcr[q] = *(const float4*)(c_buf + (size_t)(2 * pgn[q] + 2) * 64 + jb);
            } else {
                pcl[q] = *(const float4*)(Cin + (2 * idx) * 68 + jb);
                pcr[q] = *(const float4*)(Cin + (2 * idx + 1) * 68 + jb);
            }
        }

        // ---- compute tiles ----
        float* Cout = (float*)(Anx + mn * A_PAD);
#pragma unroll
        for (int q = 0; q < NQ; q++) {
            f32x4 acc[5];
#pragma unroll
            for (int g = 0; g < 5; g++) acc[g] = (f32x4){0.f, 0.f, 0.f, 0.f};
#pragma unroll
            for (int kb = 0; kb < 6; kb++) {
                bf16x8 nf = *(const bf16x8*)(&Acur[pidx[q] * A_PAD + kb * 32 + quad * 8]);
#pragma unroll
                for (int g = 0; g < 5; g++)
                    acc[g] = __builtin_amdgcn_mfma_f32_16x16x32_bf16(Wf[g][kb], nf, acc[g], 0, 0, 0);
            }
            float4 c4, h4;
            gates(acc, bI, bO, bU, bL, bR, pcl[q], pcr[q], c4, h4);
            if (pact[q]) {
                union { bf16 h[4]; uint2 u; } hp;
                const float* ph4 = &h4.x;
#pragma unroll
                for (int r = 0; r < 4; r++) hp.h[r] = (bf16)ph4[r];
                if (l > 8) {
                    *(float4*)(Cout + pidx[q] * 68 + jb) = c4;
                    *(uint2*)(&Anx[(pidx[q] >> 1) * A_PAD + 64 + (pidx[q] & 1) * 64 + jb]) = hp.u;
                } else {
                    *(float4*)(c_buf + (size_t)pgn[q] * 64 + jb) = c4;
                    *(uint2*)(H + (size_t)pgn[q] * 64 + jb) = hp.u;
                }
            }
        }
    }

    // ---- staging split part B: gather + LDS write (token arrived under compute) ----
    if (sact) {
        uint4 g = *(const uint4*)(emb16 + (size_t)tok * 64 + sk8);
        *(uint4*)(&Anx[srow * A_PAD + sk8]) = g;
    }
    __syncthreads();
}

// ---- dispatch 2: levels 16..8, 256 blocks x 512 thr (one 8-wave chain per
// CU, LDS 153.6 KB). c via LDS for levels 15..8, register-prefetched c,
// async staging split. __launch_bounds__(512,1): effective VGPR cap =
// 256/max(arg, block_waves/4) = 128 — the only config that fits this
// ~124-VGPR body (R3/R5/R11/R13 post-mortems: every other block shape
// spills catastrophically; FETCH explosion is the revert signal). ----
__global__ __launch_bounds__(512, 1) void big_pass(
        const bf16* __restrict__ Wcat, const float* __restrict__ bias,
        const bf16* __restrict__ emb16, const int* __restrict__ token_ids,
        const bf16* __restrict__ leafH, const float* __restrict__ leafC,
        bf16* __restrict__ H, float* __restrict__ c_buf) {
    __shared__ __align__(16) bf16 A0[256 * A_PAD];   // 102400 B
    __shared__ __align__(16) bf16 A1[128 * A_PAD];   //  51200 B (total 153600 B)
    const int tid = threadIdx.x, blk = blockIdx.x;
    const int wave = tid >> 6, lane = tid & 63;
    const int l15 = lane & 15, quad = lane >> 4;
    const int wj = wave & 3, wt = wave >> 2;
    const int jw = wj * 16, jb = jw + quad * 4;

    const int base16 = 65535 + blk * 256;            // first level-16 node of this block

    // ---- stage level-16 tile: x (token emb gather) + children h (leaf table) ----
    for (int ch = tid; ch < 256 * 8; ch += 512) {
        int row = ch >> 3, k8 = (ch & 7) << 3;
        int tok = token_ids[base16 + row];
        *(uint4*)&A0[row * A_PAD + k8] = *(const uint4*)(emb16 + tok * 64 + k8);
    }
    for (int ch = tid; ch < 256 * 16; ch += 512) {
        int row = ch >> 4, half = (ch >> 3) & 1, k8 = (ch & 7) << 3;
        int tok = token_ids[2 * (base16 + row) + 1 + half];
        *(uint4*)&A0[row * A_PAD + 64 + half * 64 + k8] = *(const uint4*)(leafH + (size_t)tok * 64 + k8);
    }

    // prefetch level-16 epilogue grandchild tokens (leafC 1-hop later)
    int tkl16[8], tkr16[8];
#pragma unroll
    for (int q = 0; q < 8; q++) {
        int idx = (wt + 2 * q) * 16 + l15;
        int gn = base16 + idx;
        tkl16[q] = token_ids[2 * gn + 1];
        tkr16[q] = token_ids[2 * gn + 2];
    }
    // prefetch level-15 staging tokens (128 rows x 8 -> 2 items/thread)
    const int rowa = tid >> 3, k8a = (tid & 7) << 3;
    const int rowb = (tid + 512) >> 3, k8b = k8a;
    const int tok15a = token_ids[32767 + blk * 128 + rowa];
    const int tok15b = token_ids[32767 + blk * 128 + rowb];

    // loop-invariant W fragments -> registers (30 x bf16x8), reused for 9 levels
    bf16x8 Wf[5][6];
#pragma unroll
    for (int g = 0; g < 5; g++)
#pragma unroll
        for (int kb = 0; kb < 6; kb++)
            Wf[g][kb] = *(const bf16x8*)(Wcat + (g * 64 + jw + l15) * KDIM + kb * 32 + quad * 8);

    const float4 bI = *(const float4*)(bias + jb);
    const float4 bO = *(const float4*)(bias + 64 + jb);
    const float4 bU = *(const float4*)(bias + 128 + jb);
    const float4 bL = *(const float4*)(bias + 192 + jb);
    const float4 bR = *(const float4*)(bias + 256 + jb);
    __syncthreads();

    // ---- level 16: 16 tiles, two groups of 4 with reg-prefetched leafC c ----
#pragma unroll
    for (int grp = 0; grp < 2; grp++) {
        float4 cl4[4], cr4[4];
#pragma unroll
        for (int q = 0; q < 4; q++) {
            cl4[q] = *(const float4*)(leafC + (size_t)tkl16[grp * 4 + q] * 64 + jb);
            cr4[q] = *(const float4*)(leafC + (size_t)tkr16[grp * 4 + q] * 64 + jb);
        }
#pragma unroll
        for (int q = 0; q < 4; q++) {
            const int idx = (wt + 2 * (grp * 4 + q)) * 16 + l15;     // < 256 always
            const int gn = base16 + idx;
            f32x4 acc[5];
#pragma unroll
            for (int g = 0; g < 5; g++) acc[g] = (f32x4){0.f, 0.f, 0.f, 0.f};
#pragma unroll
            for (int kb = 0; kb < 6; kb++) {
                bf16x8 nf = *(const bf16x8*)(&A0[idx * A_PAD + kb * 32 + quad * 8]);
#pragma unroll
                for (int g = 0; g < 5; g++)
                    acc[g] = __builtin_amdgcn_mfma_f32_16x16x32_bf16(Wf[g][kb], nf, acc[g], 0, 0, 0);
            }
            float4 c4, h4;
            gates(acc, bI, bO, bU, bL, bR, cl4[q], cr4[q], c4, h4);
            union { bf16 h[4]; uint2 u; } hp;
            const float* ph4 = &h4.x;
#pragma unroll
            for (int r = 0; r < 4; r++) hp.h[r] = (bf16)ph4[r];
            *(float4*)(c_buf + (size_t)gn * 64 + jb) = c4;           // level-16 c: global (L2)
            *(uint2*)(&A1[(idx >> 1) * A_PAD + 64 + (idx & 1) * 64 + jb]) = hp.u;
        }
        if (grp == 0) {
            // issue level-15 x gathers (tokens arrived under group-0 compute)
            uint4 ga = *(const uint4*)(emb16 + (size_t)tok15a * 64 + k8a);
            uint4 gb = *(const uint4*)(emb16 + (size_t)tok15b * 64 + k8b);
            *(uint4*)(&A1[rowa * A_PAD + k8a]) = ga;
            *(uint4*)(&A1[rowb * A_PAD + k8b]) = gb;
        }
    }
    __syncthreads();

    // ---- levels 15..8 via level_phase; c through LDS from 15 down ----
    bf16* Acur = A1;
    bf16* Anx  = A0;
    level_phase<4, true >(15, blk, tid, wt, l15, quad, jb, Wf, bI, bO, bU, bL, bR,
                          Acur, Anx, emb16, token_ids, H, c_buf);
    { bf16* t = Acur; Acur = Anx; Anx = t; }
    level_phase<2, false>(14, blk, tid, wt, l15, quad, jb, Wf, bI, bO, bU, bL, bR,
                          Acur, Anx, emb16, token_ids, H, c_buf);
    { bf16* t = Acur; Acur = Anx; Anx = t; }
    for (int l = 13; l >= 8; l--) {
        level_phase<1, false>(l, blk, tid, wt, l15, quad, jb, Wf, bI, bO, bU, bL, bR,
                              Acur, Anx, emb16, token_ids, H, c_buf);
        bf16* t = Acur; Acur = Anx; Anx = t;
    }
}

// ---- dispatch 3: levels 7..0, ONE block x 512 thr (8 waves), fully
// LDS-resident. All global gathers hoisted into one overlapped staging phase
// before the first barrier; inter-level h in one packed A-tile, inter-level c
// ping-pongs between two LDS f32 buffers. ----
__global__ __launch_bounds__(512) void tail_pass(
        const bf16* __restrict__ Wcat, const float* __restrict__ bias,
        const bf16* __restrict__ emb16, const int* __restrict__ token_ids,
        const bf16* __restrict__ H, const float* __restrict__ c_buf,
        float* __restrict__ out) {
    __shared__ __align__(16) bf16 A[255 * A_PAD];   // 102000 B: x+h for levels 7..0
    __shared__ __align__(16) float C0[128 * 68];    //  34816 B
    __shared__ __align__(16) float C1[64 * 68];     //  17408 B  (total 154224 B)
    const int tid = threadIdx.x;
    const int wave = tid >> 6, lane = tid & 63;
    const int l15 = lane & 15, quad = lane >> 4;
    const int wj = wave & 3, wt = wave >> 2;
    const int jw = wj * 16, jb = jw + quad * 4;

    // prefetch level-7 children c (level-8 c_buf) into regs; fully unrolled so
    // cl7/cr7 stay in VGPRs. Latency overlaps the LDS staging below.
    float4 cl7[4], cr7[4];
#pragma unroll
    for (int q = 0; q < 4; q++) {
        int idx = (wt + 2 * q) * 16 + l15;
        int gn = 127 + idx;
        cl7[q] = *(const float4*)(c_buf + (size_t)(2 * gn + 1) * 64 + jb);
        cr7[q] = *(const float4*)(c_buf + (size_t)(2 * gn + 2) * 64 + jb);
    }

    // stage x (emb16 gather) for ALL levels 7..0: row r -> level l = 31-clz(255-r),
    // idx = r - (256 - 2^(l+1)); 2040 independent 16B loads across 512 threads.
    for (int ch = tid; ch < 255 * 8; ch += 512) {
        int row = ch >> 3, k8 = (ch & 7) << 3;
        int l = 31 - __clz(255 - row);
        int idx = row - 256 + (2 << l);
        int gn = (1 << l) - 1 + idx;
        int tok = token_ids[gn];
        *(uint4*)&A[row * A_PAD + k8] = *(const uint4*)(emb16 + tok * 64 + k8);
    }
    // stage level-7 children h (level-8 H rows, contiguous sibling pairs)
    for (int ch = tid; ch < 128 * 16; ch += 512) {
        int row = ch >> 4, k8 = (ch & 15) << 3;
        *(uint4*)&A[row * A_PAD + 64 + k8] =
            *(const uint4*)(H + (size_t)(255 + 2 * row) * 64 + k8);
    }

    // loop-invariant W fragments
    bf16x8 Wf[5][6];
#pragma unroll
    for (int g = 0; g < 5; g++)
#pragma unroll
        for (int kb = 0; kb < 6; kb++)
            Wf[g][kb] = *(const bf16x8*)(Wcat + (g * 64 + jw + l15) * KDIM + kb * 32 + quad * 8);

    const float4 bI = *(const float4*)(bias + jb);
    const float4 bO = *(const float4*)(bias + 64 + jb);
    const float4 bU = *(const float4*)(bias + 128 + jb);
    const float4 bL = *(const float4*)(bias + 192 + jb);
    const float4 bR = *(const float4*)(bias + 256 + jb);
    __syncthreads();

    // ---- level 7 (128 nodes, 8 tiles; c from prefetched regs) ----
#pragma unroll
    for (int q = 0; q < 4; q++) {
        const int idx = (wt + 2 * q) * 16 + l15;     // < 128 always
        f32x4 acc[5];
#pragma unroll
        for (int g = 0; g < 5; g++) acc[g] = (f32x4){0.f, 0.f, 0.f, 0.f};
#pragma unroll
        for (int kb = 0; kb < 6; kb++) {
            bf16x8 nf = *(const bf16x8*)(&A[idx * A_PAD + kb * 32 + quad * 8]);
#pragma unroll
            for (int g = 0; g < 5; g++)
                acc[g] = __builtin_amdgcn_mfma_f32_16x16x32_bf16(Wf[g][kb], nf, acc[g], 0, 0, 0);
        }
        float4 c4, h4;
        gates(acc, bI, bO, bU, bL, bR, cl7[q], cr7[q], c4, h4);
        union { bf16 h[4]; uint2 u; } hp;
        const float* ph4 = &h4.x;
#pragma unroll
        for (int r = 0; r < 4; r++) hp.h[r] = (bf16)ph4[r];
        *(float4*)(C0 + idx * 68 + jb) = c4;                               // level-7 c
        *(uint2*)(&A[(128 + (idx >> 1)) * A_PAD + 64 + (idx & 1) * 64 + jb]) = hp.u;
    }
    __syncthreads();

    // ---- levels 6..0, all data in LDS ----
    float* Ccur = C0;
    float* Cnx  = C1;
    for (int l = 6; l >= 0; l--) {
        const int n = 1 << l;
        const int off  = 256 - 2 * n;    // this level's A-row offset
        const int offn = 256 - n;        // next (parent) level's A-row offset
        const int T = (n + 15) >> 4;
        for (int ti = wt; ti < T; ti += 2) {
            int idx0 = ti * 16 + l15;
            int idx = idx0 < n ? idx0 : n - 1;
            float4 cl = *(const float4*)(Ccur + (2 * idx) * 68 + jb);
            float4 cr = *(const float4*)(Ccur + (2 * idx + 1) * 68 + jb);
            f32x4 acc[5];
#pragma unroll
            for (int g = 0; g < 5; g++) acc[g] = (f32x4){0.f, 0.f, 0.f, 0.f};
#pragma unroll
            for (int kb = 0; kb < 6; kb++) {
                bf16x8 nf = *(const bf16x8*)(&A[(off + idx) * A_PAD + kb * 32 + quad * 8]);
#pragma unroll
                for (int g = 0; g < 5; g++)
                    acc[g] = __builtin_amdgcn_mfma_f32_16x16x32_bf16(Wf[g][kb], nf, acc[g], 0, 0, 0);
            }
            float4 c4, h4;
            gates(acc, bI, bO, bU, bL, bR, cl, cr, c4, h4);
            if (idx0 < n) {
                if (l > 0) {
                    union { bf16 h[4]; uint2 u; } hp;
                    const float* ph4 = &h4.x;
#pragma unroll
                    for (int r = 0; r < 4; r++) hp.h[r] = (bf16)ph4[r];
                    *(float4*)(Cnx + idx * 68 + jb) = c4;
                    *(uint2*)(&A[(offn + (idx >> 1)) * A_PAD + 64 + (idx & 1) * 64 + jb]) = hp.u;
                } else {
                    *(float4*)(out + jb) = h4;        // stack([h, c]): h
                    *(float4*)(out + 64 + jb) = c4;   // c
                }
            }
        }
        __syncthreads();
        float* t = Ccur; Ccur = Cnx; Cnx = t;
    }
}

extern "C" void kernel_launch(void* const* d_in, const int* in_sizes, int n_in,
                              void* d_out, int out_size, void* d_ws, size_t ws_size,
                              hipStream_t stream) {
    const int*   token_ids = (const int*)d_in[0];
    const float* emb       = (const float*)d_in[1];
    const float* W_iou     = (const float*)d_in[2];
    const float* b_Wiou    = (const float*)d_in[3];
    const float* U_iou     = (const float*)d_in[4];
    const float* b_Uiou    = (const float*)d_in[5];
    const float* W_f       = (const float*)d_in[6];
    const float* b_Wf      = (const float*)d_in[7];
    const float* U_f       = (const float*)d_in[8];
    const float* b_Uf      = (const float*)d_in[9];
    float* out = (float*)d_out;

    // Compact workspace (~34.8 MB): H holds only level-8 h (512 rows);
    // c_buf holds nodes < 131072 (level-16 + level-8 writes only —
    // levels 15..9 c passes through LDS inside big_pass).
    char* ws = (char*)d_ws;
    bf16*  Wcat  = (bf16*)ws;                               // 122880 B
    float* bias  = (float*)(ws + 122880);                   // 1280 B -> 124160
    bf16*  emb16 = (bf16*)(ws + 124160);                    // 262144 B -> 386304
    bf16*  leafH = (bf16*)(ws + 386304);                    // 262144 B -> 648448
    float* leafC = (float*)(ws + 648448);                   // 524288 B -> 1172736
    bf16*  H     = (bf16*)(ws + 1172736);                   // 65536 B -> 1238272
    float* c_buf = (float*)(ws + 1238272);                  // 33554432 B -> 34792704

    prep_all<<<544, 256, 0, stream>>>(emb, W_iou, U_iou, W_f, U_f,
                                      b_Wiou, b_Uiou, b_Wf, b_Uf,
                                      Wcat, bias, emb16, leafH, leafC);
    big_pass<<<256, 512, 0, stream>>>(Wcat, bias, emb16, token_ids, leafH, leafC, H, c_buf);
    tail_pass<<<1, 512, 0, stream>>>(Wcat, bias, emb16, token_ids, H, c_buf, out);
}